// Round 3
// baseline (2354.645 us; speedup 1.0000x reference)
//
#include <hip/hip_runtime.h>
#include <hip/hip_bf16.h>

#define N_TOK 16384
#define C_DIM 1024
#define H_DIM 4096
#define E_NUM 8
#define NK_TOT 32768

typedef unsigned short u16;
typedef unsigned int u32;
typedef float f4 __attribute__((ext_vector_type(4)));
typedef __bf16 bf8 __attribute__((ext_vector_type(8)));

union V16 { f4 f; bf8 b; };

__device__ __forceinline__ u16 f2bf(float x) {
  // round-to-nearest-even fp32 -> bf16
  u32 u = __builtin_bit_cast(u32, x);
  u = (u + 0x7fffu + ((u >> 16) & 1u)) >> 16;
  return (u16)u;
}

// ---------------- x fp32 -> bf16 ----------------
__global__ __launch_bounds__(256) void cvt_x_k(const float* __restrict__ src, u16* __restrict__ dst) {
  const size_t g = (size_t)blockIdx.x * 256 + threadIdx.x;   // over N*C/4
  const f4 v = ((const f4*)src)[g];
  u32 lo = (u32)f2bf(v[0]) | ((u32)f2bf(v[1]) << 16);
  u32 hi = (u32)f2bf(v[2]) | ((u32)f2bf(v[3]) << 16);
  ((uint2*)dst)[g] = make_uint2(lo, hi);
}

// ------------- weight transpose + cvt: src fp32 [R][S] -> dst bf16 [S][R], per expert (grid.z) -------------
__global__ __launch_bounds__(256) void transpose_cvt_k(const float* __restrict__ src, u16* __restrict__ dst,
                                                       int R, int S) {
  __shared__ float tile[64][65];
  const size_t eoff = (size_t)blockIdx.z * R * S;
  const int s0 = blockIdx.x * 64, r0 = blockIdx.y * 64;
  for (int p = threadIdx.x; p < 4096; p += 256) {
    int r = p >> 6, s = p & 63;
    tile[r][s] = src[eoff + (size_t)(r0 + r) * S + (s0 + s)];
  }
  __syncthreads();
  for (int p = threadIdx.x; p < 4096; p += 256) {
    int sN = p >> 6, rN = p & 63;
    dst[eoff + (size_t)(s0 + sN) * R + (r0 + rN)] = f2bf(tile[rN][sN]);
  }
}

// ---------------- router: one wave per token ----------------
__global__ __launch_bounds__(256) void router_k(const float* __restrict__ x, const float* __restrict__ rw,
                                                const float* __restrict__ rb, int* __restrict__ idx,
                                                float* __restrict__ vals, u32* __restrict__ cnt,
                                                float* __restrict__ imp) {
  __shared__ float s_imp[E_NUM];
  __shared__ u32 s_cnt[E_NUM];
  if (threadIdx.x < E_NUM) { s_imp[threadIdx.x] = 0.f; s_cnt[threadIdx.x] = 0u; }
  __syncthreads();
  const int wave = threadIdx.x >> 6, lane = threadIdx.x & 63;
  const int t = blockIdx.x * 4 + wave;
  const float* xr = x + (size_t)t * C_DIM;
  float a[E_NUM] = {0.f, 0.f, 0.f, 0.f, 0.f, 0.f, 0.f, 0.f};
  for (int c = lane; c < C_DIM; c += 64) {
    float xv = xr[c];
    const float* w = rw + c * E_NUM;
#pragma unroll
    for (int e = 0; e < E_NUM; ++e) a[e] = fmaf(xv, w[e], a[e]);
  }
#pragma unroll
  for (int e = 0; e < E_NUM; ++e) {
#pragma unroll
    for (int off = 32; off > 0; off >>= 1) a[e] += __shfl_xor(a[e], off, 64);
  }
  if (lane == 0) {
    float p[E_NUM]; float m = -1e30f, s = 0.f;
#pragma unroll
    for (int e = 0; e < E_NUM; ++e) { p[e] = a[e] + rb[e]; m = fmaxf(m, p[e]); }
#pragma unroll
    for (int e = 0; e < E_NUM; ++e) { p[e] = expf(p[e] - m); s += p[e]; }
    const float inv = 1.f / s;
#pragma unroll
    for (int e = 0; e < E_NUM; ++e) p[e] *= inv;
    int e0 = 0; float v0 = p[0];
#pragma unroll
    for (int e = 1; e < E_NUM; ++e) if (p[e] > v0) { v0 = p[e]; e0 = e; }
    int e1 = -1; float v1 = -1e30f;
#pragma unroll
    for (int e = 0; e < E_NUM; ++e) if (e != e0 && p[e] > v1) { v1 = p[e]; e1 = e; }
    idx[2 * t] = e0; idx[2 * t + 1] = e1;
    vals[2 * t] = v0; vals[2 * t + 1] = v1;
    atomicAdd(&s_cnt[e0], 1u); atomicAdd(&s_cnt[e1], 1u);
#pragma unroll
    for (int e = 0; e < E_NUM; ++e) atomicAdd(&s_imp[e], p[e]);
  }
  __syncthreads();
  if (threadIdx.x < E_NUM) {
    atomicAdd(&cnt[threadIdx.x], s_cnt[threadIdx.x]);
    atomicAdd(&imp[threadIdx.x], s_imp[threadIdx.x]);
  }
}

__global__ void offsets_k(const u32* __restrict__ cnt, int* __restrict__ off) {
  if (threadIdx.x == 0) {
    int s = 0;
    for (int e = 0; e < E_NUM; ++e) { off[e] = s; s += (int)cnt[e]; }
    off[E_NUM] = s;
  }
}

// ---------------- scatter tokens into per-expert lists (stride N_TOK) ----------------
__global__ __launch_bounds__(256) void scatter_k(const int* __restrict__ idx, u32* __restrict__ cursor,
                                                 int* __restrict__ tl) {
  __shared__ u32 lcnt[E_NUM];
  __shared__ u32 base[E_NUM];
  if (threadIdx.x < E_NUM) lcnt[threadIdx.x] = 0u;
  __syncthreads();
  const int t = blockIdx.x * 256 + threadIdx.x;
  const int e0 = idx[2 * t], e1 = idx[2 * t + 1];
  const u32 p0 = atomicAdd(&lcnt[e0], 1u);
  const u32 p1 = atomicAdd(&lcnt[e1], 1u);
  __syncthreads();
  if (threadIdx.x < E_NUM) base[threadIdx.x] = atomicAdd(&cursor[threadIdx.x], lcnt[threadIdx.x]);
  __syncthreads();
  tl[e0 * N_TOK + (int)(base[e0] + p0)] = t;
  tl[e1 * N_TOK + (int)(base[e1] + p1)] = t;
}

// ---------------- grouped GEMM: 256x256 tile, BK=64, 8 waves (2Mx4N), mfma 16x16x32 bf16 ----------------
// Phase-split schedule with COUNTED vmcnt (T3+T4):
//   LDS = [2 buf][2 k-half][256 rows][32 k] bf16 (128 KiB). One phase consumes one k-half.
//   Stage S(kt,kh) = 32 KB (A+B half) = 4 global_load_lds dwordx4 per thread.
//   Issue: S(kt+1,kh1) in phase A of kt; S(kt+2,kh0) in phase B of kt.
//   Steady state: 3 stages (12 loads) in flight; phase waits are vmcnt(8) -> oldest stage
//   (the one the next phase reads) retired; never drain to 0 in the main loop.
//   Barriers carry lgkmcnt(0) so in-flight ds_reads can't straddle an overwrite (rule-18 analog).
// ds_read swizzle for 64B rows: slot = quad ^ (l16&3) ^ ((l16>>2)&3)  -> worst 2-way (free, m136).
// Source is pre-swizzled with the same involution (rule 21), LDS dest stays linear.
// MODE 0: h = relu(gather(x_bf) @ w1t^T + b1)  -> h_out (bf16)
// MODE 1: out_acc[token] += h @ w2t^T          (fp32 atomicAdd into d_out)
template <int MODE>
__global__ __launch_bounds__(512, 2) void moe_gemm(
    const u16* __restrict__ A_base, const u16* __restrict__ Bt, const float* __restrict__ bias,
    u16* __restrict__ h_out, float* out_acc, const int* __restrict__ token_list,
    const u32* __restrict__ counts, const int* __restrict__ offsets,
    int K_len, int B_stride, int B_ncap, int n_base, int k_off, int A_stride, int h_stride) {
  const int e = blockIdx.z;
  const int n_e = (int)counts[e];
  const int m0 = blockIdx.x * 256;
  if (m0 >= n_e) return;
  const int off_e = offsets[e];
  const int nb = blockIdx.y * 256;

  __shared__ u16 lA[2][2][8192];   // [buf][khalf][256 rows x 32 k]
  __shared__ u16 lB[2][2][8192];

  const int tid = threadIdx.x;
  const int lane = tid & 63;
  const int wave = tid >> 6;

  // Staging addresses. Per stage (one k-half): 1024 16B-slots; thread t, round q owns
  // slot p = q*512+t -> row = p>>2 (64B rows), c4 = p&3. Source slot pre-swizzled by the
  // read involution c4 ^ (row&3) ^ ((row>>2)&3).
  const u16* a_srcp[2]; const u16* b_srcp[2];
#pragma unroll
  for (int q = 0; q < 2; ++q) {
    const int p = q * 512 + tid;
    const int lrow = p >> 2;
    const int ss = (p & 3) ^ (lrow & 3) ^ ((lrow >> 2) & 3);
    int ar = m0 + lrow; if (ar > n_e - 1) ar = n_e - 1;   // clamp tail rows
    size_t arow;
    if (MODE == 0) arow = (size_t)token_list[e * N_TOK + ar] * A_stride;
    else           arow = (size_t)(off_e + ar) * A_stride;
    a_srcp[q] = A_base + arow + ss * 8;
    b_srcp[q] = Bt + ((size_t)e * B_ncap + (n_base + nb + lrow)) * B_stride + k_off + ss * 8;
  }

  // issue one stage: A+B k-half (kb = k offset in u16 incl. kh*32) into [buf][kh]
  auto STAGE = [&](int buf, int kh, int kb) {
#pragma unroll
    for (int q = 0; q < 2; ++q) {
      __builtin_amdgcn_global_load_lds(
          (const __attribute__((address_space(1))) void*)(a_srcp[q] + kb),
          (__attribute__((address_space(3))) void*)(&lA[buf][kh][q * 4096 + wave * 512]),
          16, 0, 0);
      __builtin_amdgcn_global_load_lds(
          (const __attribute__((address_space(1))) void*)(b_srcp[q] + kb),
          (__attribute__((address_space(3))) void*)(&lB[buf][kh][q * 4096 + wave * 512]),
          16, 0, 0);
    }
  };

  f4 acc[8][4];
#pragma unroll
  for (int i = 0; i < 8; ++i)
#pragma unroll
    for (int j = 0; j < 4; ++j) acc[i][j] = (f4){0.f, 0.f, 0.f, 0.f};

  const int quad = lane >> 4, l16 = lane & 15;
  const int wm2 = (wave >> 2) * 128;   // wave M-group: 0..1 -> rows 0/128
  const int wn4 = (wave & 3) * 64;     // wave N-group: 0..3 -> cols 0/64/128/192
  const int slot8 = (quad ^ ((l16 & 3) ^ ((l16 >> 2) & 3))) * 8;  // swizzled 16B slot (u16 units)

  // one compute phase: consume k-half kk of buffer buf (12 ds_read_b128 + 32 MFMA)
  auto PHASE = [&](int buf, int kk) {
    const u16* LA = &lA[buf][kk][0];
    const u16* LB = &lB[buf][kk][0];
    V16 af[8], bv[4];
#pragma unroll
    for (int i = 0; i < 8; ++i) af[i].f = *(const f4*)&LA[(wm2 + i * 16 + l16) * 32 + slot8];
#pragma unroll
    for (int j = 0; j < 4; ++j) bv[j].f = *(const f4*)&LB[(wn4 + j * 16 + l16) * 32 + slot8];
#pragma unroll
    for (int i = 0; i < 8; ++i)
#pragma unroll
      for (int j = 0; j < 4; ++j)
        acc[i][j] = __builtin_amdgcn_mfma_f32_16x16x32_bf16(af[i].b, bv[j].b, acc[i][j], 0, 0, 0);
  };

  const int T = K_len >> 6;   // K-tiles (>= 2 always: K_len >= 128)

  // prologue: S(0,0) S(0,1) S(1,0); wait oldest stage, barrier
  STAGE(0, 0, 0);
  STAGE(0, 1, 32);
  STAGE(1, 0, 64);
  asm volatile("s_waitcnt vmcnt(8)\n\ts_barrier" ::: "memory");

  // main loop: steady-state waits vmcnt(8) (3 stages in flight, oldest retired)
  for (int kt = 0; kt + 2 < T; ++kt) {
    const int buf = kt & 1;
    const int kb = kt * 64;
    STAGE(buf ^ 1, 1, kb + 96);            // S(kt+1, kh1)
    PHASE(buf, 0);
    asm volatile("s_waitcnt vmcnt(8) lgkmcnt(0)\n\ts_barrier" ::: "memory");
    STAGE(buf, 0, kb + 128);               // S(kt+2, kh0) (same buffer parity)
    PHASE(buf, 1);
    asm volatile("s_waitcnt vmcnt(8) lgkmcnt(0)\n\ts_barrier" ::: "memory");
  }
  { // kt = T-2: still prefetches S(T-1,kh1); phase-B wait tightens to vmcnt(4)
    const int buf = (T - 2) & 1;
    const int kb = (T - 2) * 64;
    STAGE(buf ^ 1, 1, kb + 96);            // S(T-1, kh1)
    PHASE(buf, 0);
    asm volatile("s_waitcnt vmcnt(8) lgkmcnt(0)\n\ts_barrier" ::: "memory");
    PHASE(buf, 1);
    asm volatile("s_waitcnt vmcnt(4) lgkmcnt(0)\n\ts_barrier" ::: "memory");
  }
  { // kt = T-1: no prefetch; drain remaining stage before its k-half
    const int buf = (T - 1) & 1;
    PHASE(buf, 0);
    asm volatile("s_waitcnt vmcnt(0)" ::: "memory");
    PHASE(buf, 1);
  }

  // epilogue; C/D layout: col = lane&15, row = quad*4 + reg
#pragma unroll
  for (int i = 0; i < 8; ++i) {
    const int lm = wm2 + i * 16 + quad * 4;
#pragma unroll
    for (int j = 0; j < 4; ++j) {
      const int ncol = nb + wn4 + j * 16 + l16;
#pragma unroll
      for (int r = 0; r < 4; ++r) {
        const int row = m0 + lm + r;
        if (row < n_e) {
          float v = acc[i][j][r];
          if (MODE == 0) {
            v += bias[e * H_DIM + n_base + ncol];
            v = fmaxf(v, 0.f);
            h_out[(size_t)(off_e + row) * h_stride + ncol] = f2bf(v);
          } else {
            const int tok = token_list[e * N_TOK + row];
            atomicAdd(&out_acc[(size_t)tok * C_DIM + ncol], v);
          }
        }
      }
    }
  }
}

// ---------------- final (in place on fp32 d_out): out = w*(acc + b2[e0] + b2[e1]); aux ----------------
__global__ __launch_bounds__(256) void final_k(float* out, const float* __restrict__ vals,
                                               const int* __restrict__ idx, const float* __restrict__ b2,
                                               const u32* __restrict__ cnt, const float* __restrict__ imp) {
  const size_t g = (size_t)blockIdx.x * 256 + threadIdx.x;  // over N*C/4
  const int t = (int)(g >> 8);
  const int c4 = (int)(g & 255);
  const float w = vals[t];  // faithful quirk: w_tok[t] = topk_vals.flat[t]
  const int e0 = idx[2 * t], e1 = idx[2 * t + 1];
  f4 a = ((const f4*)out)[g];
  f4 u = ((const f4*)(b2 + (size_t)e0 * C_DIM))[c4];
  f4 v = ((const f4*)(b2 + (size_t)e1 * C_DIM))[c4];
  f4 r;
#pragma unroll
  for (int q = 0; q < 4; ++q) r[q] = w * (a[q] + u[q] + v[q]);
  ((f4*)out)[g] = r;
  if (g == 0) {
    float aux = 0.f;
    for (int e = 0; e < E_NUM; ++e)
      aux += (imp[e] / (float)N_TOK) * ((float)cnt[e] / (float)(N_TOK * 2));
    out[(size_t)N_TOK * C_DIM] = aux;
  }
}

extern "C" void kernel_launch(void* const* d_in, const int* in_sizes, int n_in,
                              void* d_out, int out_size, void* d_ws, size_t ws_size,
                              hipStream_t stream) {
  const float* x  = (const float*)d_in[0];
  const float* rw = (const float*)d_in[1];
  const float* rb = (const float*)d_in[2];
  const float* w1 = (const float*)d_in[3];
  const float* b1 = (const float*)d_in[4];
  const float* w2 = (const float*)d_in[5];
  const float* b2 = (const float*)d_in[6];
  float* out = (float*)d_out;   // fp32 output (reference returns float32)

  char* ws = (char*)d_ws;
  size_t off = 0;
  auto alloc = [&](size_t bytes) -> void* {
    void* p = ws + off; off += (bytes + 255) & ~(size_t)255; return p;
  };
  u16* x_bf    = (u16*)alloc((size_t)N_TOK * C_DIM * 2);
  u16* w1t     = (u16*)alloc((size_t)E_NUM * H_DIM * C_DIM * 2);
  u16* w2t     = (u16*)alloc((size_t)E_NUM * C_DIM * H_DIM * 2);
  int* tl      = (int*)alloc((size_t)E_NUM * N_TOK * 4);
  int* idx     = (int*)alloc((size_t)N_TOK * 2 * 4);
  float* vals  = (float*)alloc((size_t)N_TOK * 2 * 4);
  u32* small   = (u32*)alloc(256);
  u32* cnt     = small;                 // [8]
  u32* cursor  = small + 8;             // [8]
  float* imp   = (float*)(small + 16);  // [8]
  int* offs    = (int*)(small + 24);    // [9]

  // h buffer: chunk H if workspace is tight (Hc must stay >= 256 for the 256-wide tile)
  size_t rem = (ws_size > off) ? ws_size - off : 0;
  int NC = 1;
  while (NC < 16 && (size_t)NK_TOT * (H_DIM / NC) * 2 > rem) NC <<= 1;
  const int Hc = H_DIM / NC;
  u16* h_buf = (u16*)(ws + off);

  // zero the fp32 accumulator (= d_out; timed replays poison it to 0xAA)
  hipMemsetAsync(out, 0, (size_t)out_size * sizeof(float), stream);
  hipMemsetAsync(small, 0, 256, stream);

  cvt_x_k<<<(N_TOK * C_DIM / 4) / 256, 256, 0, stream>>>(x, x_bf);
  transpose_cvt_k<<<dim3(H_DIM / 64, C_DIM / 64, E_NUM), 256, 0, stream>>>(w1, w1t, C_DIM, H_DIM);
  transpose_cvt_k<<<dim3(C_DIM / 64, H_DIM / 64, E_NUM), 256, 0, stream>>>(w2, w2t, H_DIM, C_DIM);
  router_k<<<N_TOK / 4, 256, 0, stream>>>(x, rw, rb, idx, vals, cnt, imp);
  offsets_k<<<1, 64, 0, stream>>>(cnt, offs);
  scatter_k<<<N_TOK / 256, 256, 0, stream>>>(idx, cursor, tl);

  for (int ci = 0; ci < NC; ++ci) {
    moe_gemm<0><<<dim3(N_TOK / 256, Hc / 256, E_NUM), 512, 0, stream>>>(
        x_bf, w1t, b1, h_buf, nullptr, tl, cnt, offs,
        /*K_len*/ C_DIM, /*B_stride*/ C_DIM, /*B_ncap*/ H_DIM,
        /*n_base*/ ci * Hc, /*k_off*/ 0, /*A_stride*/ C_DIM, /*h_stride*/ Hc);
    moe_gemm<1><<<dim3(N_TOK / 256, C_DIM / 256, E_NUM), 512, 0, stream>>>(
        h_buf, w2t, nullptr, nullptr, out, tl, cnt, offs,
        /*K_len*/ Hc, /*B_stride*/ H_DIM, /*B_ncap*/ C_DIM,
        /*n_base*/ 0, /*k_off*/ ci * Hc, /*A_stride*/ Hc, /*h_stride*/ 0);
  }

  final_k<<<(N_TOK * C_DIM / 4) / 256, 256, 0, stream>>>(out, vals, idx, b2, cnt, imp);
}

// Round 4
// 1858.143 us; speedup vs baseline: 1.2672x; 1.2672x over previous
//
#include <hip/hip_runtime.h>
#include <hip/hip_bf16.h>

#define N_TOK 16384
#define C_DIM 1024
#define H_DIM 4096
#define E_NUM 8
#define NK_TOT 32768

typedef unsigned short u16;
typedef unsigned int u32;
typedef float f4 __attribute__((ext_vector_type(4)));
typedef __bf16 bf8 __attribute__((ext_vector_type(8)));

union V16 { f4 f; bf8 b; };

#define AS1 __attribute__((address_space(1)))
#define AS3 __attribute__((address_space(3)))
#define BARRIER() asm volatile("s_barrier" ::: "memory")
#define LGKM0()   asm volatile("s_waitcnt lgkmcnt(0)" ::: "memory")
#define VMC(n)    asm volatile("s_waitcnt vmcnt(" #n ")" ::: "memory")

__device__ __forceinline__ u16 f2bf(float x) {
  // round-to-nearest-even fp32 -> bf16
  u32 u = __builtin_bit_cast(u32, x);
  u = (u + 0x7fffu + ((u >> 16) & 1u)) >> 16;
  return (u16)u;
}

// ---------------- x fp32 -> bf16 ----------------
__global__ __launch_bounds__(256) void cvt_x_k(const float* __restrict__ src, u16* __restrict__ dst) {
  const size_t g = (size_t)blockIdx.x * 256 + threadIdx.x;   // over N*C/4
  const f4 v = ((const f4*)src)[g];
  u32 lo = (u32)f2bf(v[0]) | ((u32)f2bf(v[1]) << 16);
  u32 hi = (u32)f2bf(v[2]) | ((u32)f2bf(v[3]) << 16);
  ((uint2*)dst)[g] = make_uint2(lo, hi);
}

// ------------- weight transpose + cvt: src fp32 [R][S] -> dst bf16 [S][R], per expert (grid.z) -------------
__global__ __launch_bounds__(256) void transpose_cvt_k(const float* __restrict__ src, u16* __restrict__ dst,
                                                       int R, int S) {
  __shared__ float tile[64][65];
  const size_t eoff = (size_t)blockIdx.z * R * S;
  const int s0 = blockIdx.x * 64, r0 = blockIdx.y * 64;
  for (int p = threadIdx.x; p < 4096; p += 256) {
    int r = p >> 6, s = p & 63;
    tile[r][s] = src[eoff + (size_t)(r0 + r) * S + (s0 + s)];
  }
  __syncthreads();
  for (int p = threadIdx.x; p < 4096; p += 256) {
    int sN = p >> 6, rN = p & 63;
    dst[eoff + (size_t)(s0 + sN) * R + (r0 + rN)] = f2bf(tile[rN][sN]);
  }
}

// ---------------- router: one wave per token ----------------
__global__ __launch_bounds__(256) void router_k(const float* __restrict__ x, const float* __restrict__ rw,
                                                const float* __restrict__ rb, int* __restrict__ idx,
                                                float* __restrict__ vals, u32* __restrict__ cnt,
                                                float* __restrict__ imp) {
  __shared__ float s_imp[E_NUM];
  __shared__ u32 s_cnt[E_NUM];
  if (threadIdx.x < E_NUM) { s_imp[threadIdx.x] = 0.f; s_cnt[threadIdx.x] = 0u; }
  __syncthreads();
  const int wave = threadIdx.x >> 6, lane = threadIdx.x & 63;
  const int t = blockIdx.x * 4 + wave;
  const float* xr = x + (size_t)t * C_DIM;
  float a[E_NUM] = {0.f, 0.f, 0.f, 0.f, 0.f, 0.f, 0.f, 0.f};
  for (int c = lane; c < C_DIM; c += 64) {
    float xv = xr[c];
    const float* w = rw + c * E_NUM;
#pragma unroll
    for (int e = 0; e < E_NUM; ++e) a[e] = fmaf(xv, w[e], a[e]);
  }
#pragma unroll
  for (int e = 0; e < E_NUM; ++e) {
#pragma unroll
    for (int off = 32; off > 0; off >>= 1) a[e] += __shfl_xor(a[e], off, 64);
  }
  if (lane == 0) {
    float p[E_NUM]; float m = -1e30f, s = 0.f;
#pragma unroll
    for (int e = 0; e < E_NUM; ++e) { p[e] = a[e] + rb[e]; m = fmaxf(m, p[e]); }
#pragma unroll
    for (int e = 0; e < E_NUM; ++e) { p[e] = expf(p[e] - m); s += p[e]; }
    const float inv = 1.f / s;
#pragma unroll
    for (int e = 0; e < E_NUM; ++e) p[e] *= inv;
    int e0 = 0; float v0 = p[0];
#pragma unroll
    for (int e = 1; e < E_NUM; ++e) if (p[e] > v0) { v0 = p[e]; e0 = e; }
    int e1 = -1; float v1 = -1e30f;
#pragma unroll
    for (int e = 0; e < E_NUM; ++e) if (e != e0 && p[e] > v1) { v1 = p[e]; e1 = e; }
    idx[2 * t] = e0; idx[2 * t + 1] = e1;
    vals[2 * t] = v0; vals[2 * t + 1] = v1;
    atomicAdd(&s_cnt[e0], 1u); atomicAdd(&s_cnt[e1], 1u);
#pragma unroll
    for (int e = 0; e < E_NUM; ++e) atomicAdd(&s_imp[e], p[e]);
  }
  __syncthreads();
  if (threadIdx.x < E_NUM) {
    atomicAdd(&cnt[threadIdx.x], s_cnt[threadIdx.x]);
    atomicAdd(&imp[threadIdx.x], s_imp[threadIdx.x]);
  }
}

__global__ void offsets_k(const u32* __restrict__ cnt, int* __restrict__ off) {
  if (threadIdx.x == 0) {
    int s = 0;
    for (int e = 0; e < E_NUM; ++e) { off[e] = s; s += (int)cnt[e]; }
    off[E_NUM] = s;
  }
}

// ---------------- scatter tokens into per-expert lists (stride N_TOK) ----------------
__global__ __launch_bounds__(256) void scatter_k(const int* __restrict__ idx, u32* __restrict__ cursor,
                                                 int* __restrict__ tl) {
  __shared__ u32 lcnt[E_NUM];
  __shared__ u32 base[E_NUM];
  if (threadIdx.x < E_NUM) lcnt[threadIdx.x] = 0u;
  __syncthreads();
  const int t = blockIdx.x * 256 + threadIdx.x;
  const int e0 = idx[2 * t], e1 = idx[2 * t + 1];
  const u32 p0 = atomicAdd(&lcnt[e0], 1u);
  const u32 p1 = atomicAdd(&lcnt[e1], 1u);
  __syncthreads();
  if (threadIdx.x < E_NUM) base[threadIdx.x] = atomicAdd(&cursor[threadIdx.x], lcnt[threadIdx.x]);
  __syncthreads();
  tl[e0 * N_TOK + (int)(base[e0] + p0)] = t;
  tl[e1 * N_TOK + (int)(base[e1] + p1)] = t;
}

// ======== grouped GEMM: 256x256 tile, BK=64, 8 waves, C-quadrant 4-phase schedule (m201 port) ========
// LDS: [2 buf][4 half: A0,B0,A1,B1][128 rows x 64 k] bf16, rows 128 B, 128 KiB total.
// Wave (wave>>2, wave&3) owns a 64x32 subtile of each 128x128 C-quadrant; acc[2][2][4][2] f4.
// Phases per K-tile t (buf = t&1): P1=Q00(read A0,B0) P2=Q01(read B1) P3=Q10(read A1) P4=Q11(no reads);
// A frags cached 2 phases, B frags cached across alternating phases -> 24 ds_read_b128/wave/tile.
// Stage cadence (1 half = 2 global_load_lds/thread per phase), targets dead since the previous phase:
//   P1: B1(t+1)->buf^1   P2: A0(t+2)->buf   P3: B0(t+2)->buf   P4: A1(t+2)->buf
// Waits: ONE vmcnt(6) per tile (at P4, before the trailing barrier). Outstanding ledger: after tile
// (t-1)'s wait, 3 stages (6 loads) remain = {A0,B0,A1}(t+1); tile t adds 4 -> 7 stages; vmcnt(6)
// retires the 4 oldest = exactly all of tile t+1's halves before t+1.P1 reads them.
// Overwrite safety: a half's last ds_read is drained by that phase's lgkmcnt(0) and confirmed
// block-wide by its trailing barrier; its restage issues >= 1 phase later.
// Swizzle (proven 0-conflict, round 1): read slot = ((kk<<2)|quad) ^ (row&7); source pre-swizzled
// with the same involution; LDS dest linear (rule 21).
// MODE 0: h = relu(gather(x_bf) @ w1t^T + b1) -> h_out (bf16).  MODE 1: out += h @ w2t^T (atomic fp32).
template <int MODE>
__global__ __launch_bounds__(512, 2) void moe_gemm(
    const u16* __restrict__ A_base, const u16* __restrict__ Bt, const float* __restrict__ bias,
    u16* __restrict__ h_out, float* out_acc, const int* __restrict__ token_list,
    const u32* __restrict__ counts, const int* __restrict__ offsets,
    int K_len, int B_stride, int B_ncap, int n_base, int k_off, int A_stride, int h_stride) {
  const int e = blockIdx.z;
  const int n_e = (int)counts[e];
  const int m0 = blockIdx.x * 256;
  if (m0 >= n_e) return;
  const int off_e = offsets[e];
  const int nb = blockIdx.y * 256;

  __shared__ u16 lds[2][4][8192];   // 128 KiB

  const int tid = threadIdx.x;
  const int lane = tid & 63;
  const int wave = tid >> 6;
  const int quad = lane >> 4, l16 = lane & 15;

  // ---- staging source offsets (u16 elements), pre-swizzled by the read involution ----
  u32 aoff[2][2], boff[2][2];       // [M/N-half][round]
#pragma unroll
  for (int h = 0; h < 2; ++h)
#pragma unroll
    for (int q = 0; q < 2; ++q) {
      const int p = q * 512 + tid;
      const int lrow = p >> 3;                     // row 0..127 within half
      const int slot = (p & 7) ^ (lrow & 7);       // swizzled 16B slot
      int ar = m0 + h * 128 + lrow; if (ar > n_e - 1) ar = n_e - 1;   // clamp tail rows
      u32 arow;
      if (MODE == 0) arow = (u32)token_list[e * N_TOK + ar] * (u32)A_stride;
      else           arow = (u32)(off_e + ar) * (u32)A_stride;
      aoff[h][q] = arow + slot * 8;
      boff[h][q] = (u32)(e * B_ncap + (n_base + nb + h * 128 + lrow)) * (u32)B_stride
                   + (u32)k_off + slot * 8;
    }

  // half ids in LDS: A0=0, B0=1, A1=2, B1=3
#define STAGE_A(BUF, HF, KB)                                                             \
  {                                                                                      \
    _Pragma("unroll") for (int q = 0; q < 2; ++q)                                        \
      __builtin_amdgcn_global_load_lds(                                                  \
          (const AS1 void*)(A_base + (size_t)aoff[HF][q] + (KB)),                        \
          (AS3 void*)(&lds[BUF][(HF)*2][q * 4096 + wave * 512]), 16, 0, 0);              \
  }
#define STAGE_B(BUF, HF, KB)                                                             \
  {                                                                                      \
    _Pragma("unroll") for (int q = 0; q < 2; ++q)                                        \
      __builtin_amdgcn_global_load_lds(                                                  \
          (const AS1 void*)(Bt + (size_t)boff[HF][q] + (KB)),                            \
          (AS3 void*)(&lds[BUF][(HF)*2 + 1][q * 4096 + wave * 512]), 16, 0, 0);          \
  }

  V16 af[4][2], bv0[2][2], bv1[2][2];
  const int rA0 = (wave >> 2) * 64 + l16;          // + i*16
  const int rB0 = (wave & 3) * 32 + l16;           // + j*16
  const int p7 = l16 & 7;

#define LD_A(BUF, HF)                                                                    \
  {                                                                                      \
    _Pragma("unroll") for (int i = 0; i < 4; ++i)                                        \
      _Pragma("unroll") for (int kk = 0; kk < 2; ++kk)                                   \
        af[i][kk].f = *(const f4*)&lds[BUF][(HF)*2]                                      \
            [(rA0 + i * 16) * 64 + ((((kk << 2) | quad) ^ p7) * 8)];                     \
  }
#define LD_B(BUF, HF, BV)                                                                \
  {                                                                                      \
    _Pragma("unroll") for (int j = 0; j < 2; ++j)                                        \
      _Pragma("unroll") for (int kk = 0; kk < 2; ++kk)                                   \
        BV[j][kk].f = *(const f4*)&lds[BUF][(HF)*2 + 1]                                  \
            [(rB0 + j * 16) * 64 + ((((kk << 2) | quad) ^ p7) * 8)];                     \
  }

  f4 acc[2][2][4][2];
#pragma unroll
  for (int qm = 0; qm < 2; ++qm)
#pragma unroll
    for (int qn = 0; qn < 2; ++qn)
#pragma unroll
      for (int i = 0; i < 4; ++i)
#pragma unroll
        for (int j = 0; j < 2; ++j) acc[qm][qn][i][j] = (f4){0.f, 0.f, 0.f, 0.f};

#define MF(QM, QN, BV)                                                                   \
  {                                                                                      \
    __builtin_amdgcn_s_setprio(1);                                                       \
    _Pragma("unroll") for (int i = 0; i < 4; ++i)                                        \
      _Pragma("unroll") for (int j = 0; j < 2; ++j) {                                    \
        acc[QM][QN][i][j] = __builtin_amdgcn_mfma_f32_16x16x32_bf16(                     \
            af[i][0].b, BV[j][0].b, acc[QM][QN][i][j], 0, 0, 0);                         \
        acc[QM][QN][i][j] = __builtin_amdgcn_mfma_f32_16x16x32_bf16(                     \
            af[i][1].b, BV[j][1].b, acc[QM][QN][i][j], 0, 0, 0);                         \
      }                                                                                  \
    __builtin_amdgcn_s_setprio(0);                                                       \
  }

  const int T = K_len >> 6;   // K-tiles (>= 4 always here)

  // ---- prologue: stage all 4 halves of tile 0 + first 3 of tile 1; retire tile 0 ----
  STAGE_A(0, 0, 0); STAGE_B(0, 0, 0); STAGE_A(0, 1, 0); STAGE_B(0, 1, 0);
  STAGE_A(1, 0, 64); STAGE_B(1, 0, 64); STAGE_A(1, 1, 64);
  VMC(6);
  BARRIER();

  // ---- main loop: tiles 0 .. T-2 (phase cadence; stages gated near the tail) ----
  for (int t = 0; t < T - 1; ++t) {
    const int buf = t & 1;
    const bool st2 = (t + 2 < T);
    const int kb1 = (t + 1) * 64, kb2 = (t + 2) * 64;

    // P1 = Q00
    LD_A(buf, 0); LD_B(buf, 0, bv0);
    STAGE_B(buf ^ 1, 1, kb1);                 // B1(t+1)
    BARRIER(); LGKM0();
    MF(0, 0, bv0);
    BARRIER();
    // P2 = Q01
    LD_B(buf, 1, bv1);
    if (st2) STAGE_A(buf, 0, kb2);            // A0(t+2)
    BARRIER(); LGKM0();
    MF(0, 1, bv1);
    BARRIER();
    // P3 = Q10
    LD_A(buf, 1);
    if (st2) STAGE_B(buf, 0, kb2);            // B0(t+2)
    BARRIER(); LGKM0();
    MF(1, 0, bv0);
    BARRIER();
    // P4 = Q11
    if (st2) STAGE_A(buf, 1, kb2);            // A1(t+2)
    BARRIER(); LGKM0();
    MF(1, 1, bv1);
    if (st2) { VMC(6); } else { VMC(0); }
    BARRIER();
  }

  // ---- final tile T-1: everything resident, no stages, no barriers needed ----
  {
    const int buf = (T - 1) & 1;
    LD_A(buf, 0); LD_B(buf, 0, bv0); LD_B(buf, 1, bv1);
    MF(0, 0, bv0);
    MF(0, 1, bv1);
    LD_A(buf, 1);
    MF(1, 0, bv0);
    MF(1, 1, bv1);
  }

  // ---- epilogue; C/D layout: col = lane&15, row = quad*4 + reg ----
#pragma unroll
  for (int qm = 0; qm < 2; ++qm)
#pragma unroll
    for (int i = 0; i < 4; ++i) {
      const int lm = qm * 128 + (wave >> 2) * 64 + i * 16 + quad * 4;
#pragma unroll
      for (int qn = 0; qn < 2; ++qn)
#pragma unroll
        for (int j = 0; j < 2; ++j) {
          const int ncol = nb + qn * 128 + (wave & 3) * 32 + j * 16 + l16;
#pragma unroll
          for (int r = 0; r < 4; ++r) {
            const int row = m0 + lm + r;
            if (row < n_e) {
              float v = acc[qm][qn][i][j][r];
              if (MODE == 0) {
                v += bias[e * H_DIM + n_base + ncol];
                v = fmaxf(v, 0.f);
                h_out[(size_t)(off_e + row) * h_stride + ncol] = f2bf(v);
              } else {
                const int tok = token_list[e * N_TOK + row];
                atomicAdd(&out_acc[(size_t)tok * C_DIM + ncol], v);
              }
            }
          }
        }
    }
#undef STAGE_A
#undef STAGE_B
#undef LD_A
#undef LD_B
#undef MF
}

// ---------------- final (in place on fp32 d_out): out = w*(acc + b2[e0] + b2[e1]); aux ----------------
__global__ __launch_bounds__(256) void final_k(float* out, const float* __restrict__ vals,
                                               const int* __restrict__ idx, const float* __restrict__ b2,
                                               const u32* __restrict__ cnt, const float* __restrict__ imp) {
  const size_t g = (size_t)blockIdx.x * 256 + threadIdx.x;  // over N*C/4
  const int t = (int)(g >> 8);
  const int c4 = (int)(g & 255);
  const float w = vals[t];  // faithful quirk: w_tok[t] = topk_vals.flat[t]
  const int e0 = idx[2 * t], e1 = idx[2 * t + 1];
  f4 a = ((const f4*)out)[g];
  f4 u = ((const f4*)(b2 + (size_t)e0 * C_DIM))[c4];
  f4 v = ((const f4*)(b2 + (size_t)e1 * C_DIM))[c4];
  f4 r;
#pragma unroll
  for (int q = 0; q < 4; ++q) r[q] = w * (a[q] + u[q] + v[q]);
  ((f4*)out)[g] = r;
  if (g == 0) {
    float aux = 0.f;
    for (int e = 0; e < E_NUM; ++e)
      aux += (imp[e] / (float)N_TOK) * ((float)cnt[e] / (float)(N_TOK * 2));
    out[(size_t)N_TOK * C_DIM] = aux;
  }
}

extern "C" void kernel_launch(void* const* d_in, const int* in_sizes, int n_in,
                              void* d_out, int out_size, void* d_ws, size_t ws_size,
                              hipStream_t stream) {
  const float* x  = (const float*)d_in[0];
  const float* rw = (const float*)d_in[1];
  const float* rb = (const float*)d_in[2];
  const float* w1 = (const float*)d_in[3];
  const float* b1 = (const float*)d_in[4];
  const float* w2 = (const float*)d_in[5];
  const float* b2 = (const float*)d_in[6];
  float* out = (float*)d_out;   // fp32 output (reference returns float32)

  char* ws = (char*)d_ws;
  size_t off = 0;
  auto alloc = [&](size_t bytes) -> void* {
    void* p = ws + off; off += (bytes + 255) & ~(size_t)255; return p;
  };
  u16* x_bf    = (u16*)alloc((size_t)N_TOK * C_DIM * 2);
  u16* w1t     = (u16*)alloc((size_t)E_NUM * H_DIM * C_DIM * 2);
  u16* w2t     = (u16*)alloc((size_t)E_NUM * C_DIM * H_DIM * 2);
  int* tl      = (int*)alloc((size_t)E_NUM * N_TOK * 4);
  int* idx     = (int*)alloc((size_t)N_TOK * 2 * 4);
  float* vals  = (float*)alloc((size_t)N_TOK * 2 * 4);
  u32* small   = (u32*)alloc(256);
  u32* cnt     = small;                 // [8]
  u32* cursor  = small + 8;             // [8]
  float* imp   = (float*)(small + 16);  // [8]
  int* offs    = (int*)(small + 24);    // [9]

  // h buffer: chunk H if workspace is tight (Hc must stay >= 256 for the 256-wide tile)
  size_t rem = (ws_size > off) ? ws_size - off : 0;
  int NC = 1;
  while (NC < 16 && (size_t)NK_TOT * (H_DIM / NC) * 2 > rem) NC <<= 1;
  const int Hc = H_DIM / NC;
  u16* h_buf = (u16*)(ws + off);

  // zero the fp32 accumulator (= d_out; timed replays poison it to 0xAA)
  hipMemsetAsync(out, 0, (size_t)out_size * sizeof(float), stream);
  hipMemsetAsync(small, 0, 256, stream);

  cvt_x_k<<<(N_TOK * C_DIM / 4) / 256, 256, 0, stream>>>(x, x_bf);
  transpose_cvt_k<<<dim3(H_DIM / 64, C_DIM / 64, E_NUM), 256, 0, stream>>>(w1, w1t, C_DIM, H_DIM);
  transpose_cvt_k<<<dim3(C_DIM / 64, H_DIM / 64, E_NUM), 256, 0, stream>>>(w2, w2t, H_DIM, C_DIM);
  router_k<<<N_TOK / 4, 256, 0, stream>>>(x, rw, rb, idx, vals, cnt, imp);
  offsets_k<<<1, 64, 0, stream>>>(cnt, offs);
  scatter_k<<<N_TOK / 256, 256, 0, stream>>>(idx, cursor, tl);

  for (int ci = 0; ci < NC; ++ci) {
    moe_gemm<0><<<dim3(N_TOK / 256, Hc / 256, E_NUM), 512, 0, stream>>>(
        x_bf, w1t, b1, h_buf, nullptr, tl, cnt, offs,
        /*K_len*/ C_DIM, /*B_stride*/ C_DIM, /*B_ncap*/ H_DIM,
        /*n_base*/ ci * Hc, /*k_off*/ 0, /*A_stride*/ C_DIM, /*h_stride*/ Hc);
    moe_gemm<1><<<dim3(N_TOK / 256, C_DIM / 256, E_NUM), 512, 0, stream>>>(
        h_buf, w2t, nullptr, nullptr, out, tl, cnt, offs,
        /*K_len*/ Hc, /*B_stride*/ H_DIM, /*B_ncap*/ C_DIM,
        /*n_base*/ 0, /*k_off*/ ci * Hc, /*A_stride*/ Hc, /*h_stride*/ 0);
  }

  final_k<<<(N_TOK * C_DIM / 4) / 256, 256, 0, stream>>>(out, vals, idx, b2, cnt, imp);
}

// Round 5
// 1430.899 us; speedup vs baseline: 1.6456x; 1.2986x over previous
//
#include <hip/hip_runtime.h>
#include <hip/hip_bf16.h>

#define N_TOK 16384
#define C_DIM 1024
#define H_DIM 4096
#define E_NUM 8
#define NK_TOT 32768

typedef unsigned short u16;
typedef unsigned int u32;
typedef float f4 __attribute__((ext_vector_type(4)));
typedef __bf16 bf8 __attribute__((ext_vector_type(8)));

union V16 { f4 f; bf8 b; };

#define AS1 __attribute__((address_space(1)))
#define AS3 __attribute__((address_space(3)))

__device__ __forceinline__ u16 f2bf(float x) {
  // round-to-nearest-even fp32 -> bf16
  u32 u = __builtin_bit_cast(u32, x);
  u = (u + 0x7fffu + ((u >> 16) & 1u)) >> 16;
  return (u16)u;
}

// ---------------- x fp32 -> bf16 ----------------
__global__ __launch_bounds__(256) void cvt_x_k(const float* __restrict__ src, u16* __restrict__ dst) {
  const size_t g = (size_t)blockIdx.x * 256 + threadIdx.x;   // over N*C/4
  const f4 v = ((const f4*)src)[g];
  u32 lo = (u32)f2bf(v[0]) | ((u32)f2bf(v[1]) << 16);
  u32 hi = (u32)f2bf(v[2]) | ((u32)f2bf(v[3]) << 16);
  ((uint2*)dst)[g] = make_uint2(lo, hi);
}

// ------------- weight transpose + cvt: src fp32 [R][S] -> dst bf16 [S][R], per expert (grid.z) -------------
__global__ __launch_bounds__(256) void transpose_cvt_k(const float* __restrict__ src, u16* __restrict__ dst,
                                                       int R, int S) {
  __shared__ float tile[64][65];
  const size_t eoff = (size_t)blockIdx.z * R * S;
  const int s0 = blockIdx.x * 64, r0 = blockIdx.y * 64;
  for (int p = threadIdx.x; p < 4096; p += 256) {
    int r = p >> 6, s = p & 63;
    tile[r][s] = src[eoff + (size_t)(r0 + r) * S + (s0 + s)];
  }
  __syncthreads();
  for (int p = threadIdx.x; p < 4096; p += 256) {
    int sN = p >> 6, rN = p & 63;
    dst[eoff + (size_t)(s0 + sN) * R + (r0 + rN)] = f2bf(tile[rN][sN]);
  }
}

// ---------------- router: one wave per token ----------------
__global__ __launch_bounds__(256) void router_k(const float* __restrict__ x, const float* __restrict__ rw,
                                                const float* __restrict__ rb, int* __restrict__ idx,
                                                float* __restrict__ vals, u32* __restrict__ cnt,
                                                float* __restrict__ imp) {
  __shared__ float s_imp[E_NUM];
  __shared__ u32 s_cnt[E_NUM];
  if (threadIdx.x < E_NUM) { s_imp[threadIdx.x] = 0.f; s_cnt[threadIdx.x] = 0u; }
  __syncthreads();
  const int wave = threadIdx.x >> 6, lane = threadIdx.x & 63;
  const int t = blockIdx.x * 4 + wave;
  const float* xr = x + (size_t)t * C_DIM;
  float a[E_NUM] = {0.f, 0.f, 0.f, 0.f, 0.f, 0.f, 0.f, 0.f};
  for (int c = lane; c < C_DIM; c += 64) {
    float xv = xr[c];
    const float* w = rw + c * E_NUM;
#pragma unroll
    for (int e = 0; e < E_NUM; ++e) a[e] = fmaf(xv, w[e], a[e]);
  }
#pragma unroll
  for (int e = 0; e < E_NUM; ++e) {
#pragma unroll
    for (int off = 32; off > 0; off >>= 1) a[e] += __shfl_xor(a[e], off, 64);
  }
  if (lane == 0) {
    float p[E_NUM]; float m = -1e30f, s = 0.f;
#pragma unroll
    for (int e = 0; e < E_NUM; ++e) { p[e] = a[e] + rb[e]; m = fmaxf(m, p[e]); }
#pragma unroll
    for (int e = 0; e < E_NUM; ++e) { p[e] = expf(p[e] - m); s += p[e]; }
    const float inv = 1.f / s;
#pragma unroll
    for (int e = 0; e < E_NUM; ++e) p[e] *= inv;
    int e0 = 0; float v0 = p[0];
#pragma unroll
    for (int e = 1; e < E_NUM; ++e) if (p[e] > v0) { v0 = p[e]; e0 = e; }
    int e1 = -1; float v1 = -1e30f;
#pragma unroll
    for (int e = 0; e < E_NUM; ++e) if (e != e0 && p[e] > v1) { v1 = p[e]; e1 = e; }
    idx[2 * t] = e0; idx[2 * t + 1] = e1;
    vals[2 * t] = v0; vals[2 * t + 1] = v1;
    atomicAdd(&s_cnt[e0], 1u); atomicAdd(&s_cnt[e1], 1u);
#pragma unroll
    for (int e = 0; e < E_NUM; ++e) atomicAdd(&s_imp[e], p[e]);
  }
  __syncthreads();
  if (threadIdx.x < E_NUM) {
    atomicAdd(&cnt[threadIdx.x], s_cnt[threadIdx.x]);
    atomicAdd(&imp[threadIdx.x], s_imp[threadIdx.x]);
  }
}

__global__ void offsets_k(const u32* __restrict__ cnt, int* __restrict__ off) {
  if (threadIdx.x == 0) {
    int s = 0;
    for (int e = 0; e < E_NUM; ++e) { off[e] = s; s += (int)cnt[e]; }
    off[E_NUM] = s;
  }
}

// ---------------- scatter tokens into per-expert lists (stride N_TOK) ----------------
__global__ __launch_bounds__(256) void scatter_k(const int* __restrict__ idx, u32* __restrict__ cursor,
                                                 int* __restrict__ tl) {
  __shared__ u32 lcnt[E_NUM];
  __shared__ u32 base[E_NUM];
  if (threadIdx.x < E_NUM) lcnt[threadIdx.x] = 0u;
  __syncthreads();
  const int t = blockIdx.x * 256 + threadIdx.x;
  const int e0 = idx[2 * t], e1 = idx[2 * t + 1];
  const u32 p0 = atomicAdd(&lcnt[e0], 1u);
  const u32 p1 = atomicAdd(&lcnt[e1], 1u);
  __syncthreads();
  if (threadIdx.x < E_NUM) base[threadIdx.x] = atomicAdd(&cursor[threadIdx.x], lcnt[threadIdx.x]);
  __syncthreads();
  tl[e0 * N_TOK + (int)(base[e0] + p0)] = t;
  tl[e1 * N_TOK + (int)(base[e1] + p1)] = t;
}

// ---- bijective XCD-chunked grid remap (T1, m204): each XCD gets a contiguous x-fastest span ----
__device__ __forceinline__ void xcd_remap(int& bx, int& by, int& bz) {
  const u32 nx = gridDim.x, ny = gridDim.y;
  const u32 n = nx * ny * gridDim.z;
  const u32 l = blockIdx.x + nx * (blockIdx.y + ny * blockIdx.z);
  const u32 q = n >> 3, r = n & 7;
  const u32 xcd = l & 7, i = l >> 3;
  const u32 wg = (xcd < r ? xcd * (q + 1) : r * (q + 1) + (xcd - r) * q) + i;
  bx = (int)(wg % nx);
  const u32 rest = wg / nx;
  by = (int)(rest % ny);
  bz = (int)(rest / ny);
}

// ---------------- grouped GEMM: 128(M)x256(N) tile, BK=64, 8 waves (2Mx4N), mfma 16x16x32 bf16 ----------------
// Round-1-proven structure: single-buffered LDS, stage -> sync -> compute -> sync per K-tile.
// Staging: global_load_lds dwordx4 (16B/lane), linear LDS dest, XOR-swizzled SOURCE slot
// (slot ^= row&7, 128-B rows) so swizzled ds_read_b128 fragment reads are bank-conflict-free
// (measured 0 conflicts in round 1). LDS = 16 KB (A) + 32 KB (B) = 48 KB.
// XCD remap gives each XCD a contiguous block span -> B panel (<=2 MiB) stays in that XCD's L2.
// MODE 0: h = relu(gather(x_bf) @ w1t^T + b1)  -> h_out (bf16)
// MODE 1: out_acc[token] += h @ w2t^T          (fp32 atomicAdd into d_out)
template <int MODE>
__global__ __launch_bounds__(512, 4) void moe_gemm(
    const u16* __restrict__ A_base, const u16* __restrict__ Bt, const float* __restrict__ bias,
    u16* __restrict__ h_out, float* out_acc, const int* __restrict__ token_list,
    const u32* __restrict__ counts, const int* __restrict__ offsets,
    int K_len, int B_stride, int B_ncap, int n_base, int k_off, int A_stride, int h_stride) {
  int bx, by, bz;
  xcd_remap(bx, by, bz);
  const int e = bz;
  const int n_e = (int)counts[e];
  const int m0 = bx * 128;
  if (m0 >= n_e) return;
  const int off_e = offsets[e];
  const int nb = by * 256;

  // LDS layout: [row][k(64)] bf16, 128 B per row
  __shared__ u16 lA[128 * 64];   // 16 KB
  __shared__ u16 lB[256 * 64];   // 32 KB

  const int tid = threadIdx.x;   // 0..511
  const int lane = tid & 63;
  const int wave = tid >> 6;     // 0..7

  // Staging geometry: slot p = q*512 + tid (16B units); row = p>>3, 16B-slot = p&7.
  // (q*512)>>3 = q*64 == 0 mod 8, so row&7 == (tid>>3)&7 for every round q.
  const int sub = (tid >> 3) & 7;       // == row & 7
  const int c16 = tid & 7;              // LDS 16B-slot within row
  const int gslot = c16 ^ sub;          // swizzled global 16B-slot (read-side involution)
  u32 a_off[2];                          // u16-element offsets into A_base
  u32 b_off[4];                          // u16-element offsets into Bt
#pragma unroll
  for (int q = 0; q < 2; ++q) {
    const int r = (q * 512 + tid) >> 3;               // A row 0..127
    int ar = m0 + r; if (ar > n_e - 1) ar = n_e - 1;  // clamp tail rows
    u32 arow;
    if (MODE == 0) arow = (u32)token_list[e * N_TOK + ar] * (u32)A_stride;
    else           arow = (u32)(off_e + ar) * (u32)A_stride;
    a_off[q] = arow + (u32)(gslot * 8);
  }
#pragma unroll
  for (int q = 0; q < 4; ++q) {
    const int r = (q * 512 + tid) >> 3;               // B row 0..255
    b_off[q] = (u32)(e * B_ncap + (n_base + nb + r)) * (u32)B_stride
               + (u32)k_off + (u32)(gslot * 8);
  }

  f4 acc[4][4];
#pragma unroll
  for (int i = 0; i < 4; ++i)
#pragma unroll
    for (int j = 0; j < 4; ++j) acc[i][j] = (f4){0.f, 0.f, 0.f, 0.f};

  const int quad = lane >> 4, l16 = lane & 15;
  const int wm = (wave >> 2) * 64;   // 0 or 64   (M within 128)
  const int wn = (wave & 3) * 64;    // 0..192    (N within 256)
  const int p7 = l16 & 7;            // == fragment row & 7

  const int iters = K_len >> 6;
  for (int it = 0; it < iters; ++it) {
    // ---- stage current K-tile: 2 A + 4 B global_load_lds dwordx4 per thread ----
#pragma unroll
    for (int q = 0; q < 2; ++q) {
      __builtin_amdgcn_global_load_lds(
          (const AS1 void*)(A_base + a_off[q]),
          (AS3 void*)(&lA[q * 4096 + wave * 512]), 16, 0, 0);
      a_off[q] += 64;
    }
#pragma unroll
    for (int q = 0; q < 4; ++q) {
      __builtin_amdgcn_global_load_lds(
          (const AS1 void*)(Bt + b_off[q]),
          (AS3 void*)(&lB[q * 4096 + wave * 512]), 16, 0, 0);
      b_off[q] += 64;
    }
    __syncthreads();   // drains vmcnt(0): tile resident

    // ---- compute: 2 k-substeps x 16 MFMA ----
#pragma unroll
    for (int kk = 0; kk < 2; ++kk) {
      const int sl = (((kk << 2) | quad) ^ p7) * 8;   // swizzled ds_read slot (u16 units)
      V16 af[4], bfr[4];
#pragma unroll
      for (int i = 0; i < 4; ++i) {
        af[i].f  = *(const f4*)&lA[(wm + i * 16 + l16) * 64 + sl];
        bfr[i].f = *(const f4*)&lB[(wn + i * 16 + l16) * 64 + sl];
      }
#pragma unroll
      for (int i = 0; i < 4; ++i)
#pragma unroll
        for (int j = 0; j < 4; ++j)
          acc[i][j] = __builtin_amdgcn_mfma_f32_16x16x32_bf16(af[i].b, bfr[j].b, acc[i][j], 0, 0, 0);
    }
    __syncthreads();   // all waves done reading before next overwrite
  }

  // epilogue; C/D layout: col = lane&15, row = quad*4 + reg
#pragma unroll
  for (int i = 0; i < 4; ++i) {
    const int lm = wm + i * 16 + quad * 4;
#pragma unroll
    for (int j = 0; j < 4; ++j) {
      const int ncol = nb + wn + j * 16 + l16;
#pragma unroll
      for (int r = 0; r < 4; ++r) {
        const int row = m0 + lm + r;
        if (row < n_e) {
          float v = acc[i][j][r];
          if (MODE == 0) {
            v += bias[e * H_DIM + n_base + ncol];
            v = fmaxf(v, 0.f);
            h_out[(size_t)(off_e + row) * h_stride + ncol] = f2bf(v);
          } else {
            const int tok = token_list[e * N_TOK + row];
            atomicAdd(&out_acc[(size_t)tok * C_DIM + ncol], v);
          }
        }
      }
    }
  }
}

// ---------------- final (in place on fp32 d_out): out = w*(acc + b2[e0] + b2[e1]); aux ----------------
__global__ __launch_bounds__(256) void final_k(float* out, const float* __restrict__ vals,
                                               const int* __restrict__ idx, const float* __restrict__ b2,
                                               const u32* __restrict__ cnt, const float* __restrict__ imp) {
  const size_t g = (size_t)blockIdx.x * 256 + threadIdx.x;  // over N*C/4
  const int t = (int)(g >> 8);
  const int c4 = (int)(g & 255);
  const float w = vals[t];  // faithful quirk: w_tok[t] = topk_vals.flat[t]
  const int e0 = idx[2 * t], e1 = idx[2 * t + 1];
  f4 a = ((const f4*)out)[g];
  f4 u = ((const f4*)(b2 + (size_t)e0 * C_DIM))[c4];
  f4 v = ((const f4*)(b2 + (size_t)e1 * C_DIM))[c4];
  f4 r;
#pragma unroll
  for (int q = 0; q < 4; ++q) r[q] = w * (a[q] + u[q] + v[q]);
  ((f4*)out)[g] = r;
  if (g == 0) {
    float aux = 0.f;
    for (int e = 0; e < E_NUM; ++e)
      aux += (imp[e] / (float)N_TOK) * ((float)cnt[e] / (float)(N_TOK * 2));
    out[(size_t)N_TOK * C_DIM] = aux;
  }
}

extern "C" void kernel_launch(void* const* d_in, const int* in_sizes, int n_in,
                              void* d_out, int out_size, void* d_ws, size_t ws_size,
                              hipStream_t stream) {
  const float* x  = (const float*)d_in[0];
  const float* rw = (const float*)d_in[1];
  const float* rb = (const float*)d_in[2];
  const float* w1 = (const float*)d_in[3];
  const float* b1 = (const float*)d_in[4];
  const float* w2 = (const float*)d_in[5];
  const float* b2 = (const float*)d_in[6];
  float* out = (float*)d_out;   // fp32 output (reference returns float32)

  char* ws = (char*)d_ws;
  size_t off = 0;
  auto alloc = [&](size_t bytes) -> void* {
    void* p = ws + off; off += (bytes + 255) & ~(size_t)255; return p;
  };
  u16* x_bf    = (u16*)alloc((size_t)N_TOK * C_DIM * 2);
  u16* w1t     = (u16*)alloc((size_t)E_NUM * H_DIM * C_DIM * 2);
  u16* w2t     = (u16*)alloc((size_t)E_NUM * C_DIM * H_DIM * 2);
  int* tl      = (int*)alloc((size_t)E_NUM * N_TOK * 4);
  int* idx     = (int*)alloc((size_t)N_TOK * 2 * 4);
  float* vals  = (float*)alloc((size_t)N_TOK * 2 * 4);
  u32* small   = (u32*)alloc(256);
  u32* cnt     = small;                 // [8]
  u32* cursor  = small + 8;             // [8]
  float* imp   = (float*)(small + 16);  // [8]
  int* offs    = (int*)(small + 24);    // [9]

  // h buffer: chunk H if workspace is tight (Hc must stay >= 256 for the 256-wide tile)
  size_t rem = (ws_size > off) ? ws_size - off : 0;
  int NC = 1;
  while (NC < 16 && (size_t)NK_TOT * (H_DIM / NC) * 2 > rem) NC <<= 1;
  const int Hc = H_DIM / NC;
  u16* h_buf = (u16*)(ws + off);

  // zero the fp32 accumulator (= d_out; timed replays poison it to 0xAA)
  hipMemsetAsync(out, 0, (size_t)out_size * sizeof(float), stream);
  hipMemsetAsync(small, 0, 256, stream);

  cvt_x_k<<<(N_TOK * C_DIM / 4) / 256, 256, 0, stream>>>(x, x_bf);
  transpose_cvt_k<<<dim3(H_DIM / 64, C_DIM / 64, E_NUM), 256, 0, stream>>>(w1, w1t, C_DIM, H_DIM);
  transpose_cvt_k<<<dim3(C_DIM / 64, H_DIM / 64, E_NUM), 256, 0, stream>>>(w2, w2t, H_DIM, C_DIM);
  router_k<<<N_TOK / 4, 256, 0, stream>>>(x, rw, rb, idx, vals, cnt, imp);
  offsets_k<<<1, 64, 0, stream>>>(cnt, offs);
  scatter_k<<<N_TOK / 256, 256, 0, stream>>>(idx, cursor, tl);

  for (int ci = 0; ci < NC; ++ci) {
    moe_gemm<0><<<dim3(N_TOK / 128, Hc / 256, E_NUM), 512, 0, stream>>>(
        x_bf, w1t, b1, h_buf, nullptr, tl, cnt, offs,
        /*K_len*/ C_DIM, /*B_stride*/ C_DIM, /*B_ncap*/ H_DIM,
        /*n_base*/ ci * Hc, /*k_off*/ 0, /*A_stride*/ C_DIM, /*h_stride*/ Hc);
    moe_gemm<1><<<dim3(N_TOK / 128, C_DIM / 256, E_NUM), 512, 0, stream>>>(
        h_buf, w2t, nullptr, nullptr, out, tl, cnt, offs,
        /*K_len*/ Hc, /*B_stride*/ H_DIM, /*B_ncap*/ C_DIM,
        /*n_base*/ 0, /*k_off*/ ci * Hc, /*A_stride*/ Hc, /*h_stride*/ 0);
  }

  final_k<<<(N_TOK * C_DIM / 4) / 256, 256, 0, stream>>>(out, vals, idx, b2, cnt, imp);
}

// Round 6
// 1390.204 us; speedup vs baseline: 1.6937x; 1.0293x over previous
//
#include <hip/hip_runtime.h>
#include <hip/hip_bf16.h>

#define N_TOK 16384
#define C_DIM 1024
#define H_DIM 4096
#define E_NUM 8
#define NK_TOT 32768

typedef unsigned short u16;
typedef unsigned int u32;
typedef float f4 __attribute__((ext_vector_type(4)));
typedef __bf16 bf8 __attribute__((ext_vector_type(8)));

union V16 { f4 f; bf8 b; };

#define AS1 __attribute__((address_space(1)))
#define AS3 __attribute__((address_space(3)))

__device__ __forceinline__ u16 f2bf(float x) {
  // round-to-nearest-even fp32 -> bf16
  u32 u = __builtin_bit_cast(u32, x);
  u = (u + 0x7fffu + ((u >> 16) & 1u)) >> 16;
  return (u16)u;
}

// ---------------- x fp32 -> bf16 ----------------
__global__ __launch_bounds__(256) void cvt_x_k(const float* __restrict__ src, u16* __restrict__ dst) {
  const size_t g = (size_t)blockIdx.x * 256 + threadIdx.x;   // over N*C/4
  const f4 v = ((const f4*)src)[g];
  u32 lo = (u32)f2bf(v[0]) | ((u32)f2bf(v[1]) << 16);
  u32 hi = (u32)f2bf(v[2]) | ((u32)f2bf(v[3]) << 16);
  ((uint2*)dst)[g] = make_uint2(lo, hi);
}

// ------------- weight transpose + cvt: src fp32 [R][S] -> dst bf16 [S][R], per expert (grid.z) -------------
__global__ __launch_bounds__(256) void transpose_cvt_k(const float* __restrict__ src, u16* __restrict__ dst,
                                                       int R, int S) {
  __shared__ float tile[64][65];
  const size_t eoff = (size_t)blockIdx.z * R * S;
  const int s0 = blockIdx.x * 64, r0 = blockIdx.y * 64;
  for (int p = threadIdx.x; p < 4096; p += 256) {
    int r = p >> 6, s = p & 63;
    tile[r][s] = src[eoff + (size_t)(r0 + r) * S + (s0 + s)];
  }
  __syncthreads();
  for (int p = threadIdx.x; p < 4096; p += 256) {
    int sN = p >> 6, rN = p & 63;
    dst[eoff + (size_t)(s0 + sN) * R + (r0 + rN)] = f2bf(tile[rN][sN]);
  }
}

// ---------------- router: one wave per token ----------------
__global__ __launch_bounds__(256) void router_k(const float* __restrict__ x, const float* __restrict__ rw,
                                                const float* __restrict__ rb, int* __restrict__ idx,
                                                float* __restrict__ vals, u32* __restrict__ cnt,
                                                float* __restrict__ imp) {
  __shared__ float s_imp[E_NUM];
  __shared__ u32 s_cnt[E_NUM];
  if (threadIdx.x < E_NUM) { s_imp[threadIdx.x] = 0.f; s_cnt[threadIdx.x] = 0u; }
  __syncthreads();
  const int wave = threadIdx.x >> 6, lane = threadIdx.x & 63;
  const int t = blockIdx.x * 4 + wave;
  const float* xr = x + (size_t)t * C_DIM;
  float a[E_NUM] = {0.f, 0.f, 0.f, 0.f, 0.f, 0.f, 0.f, 0.f};
  for (int c = lane; c < C_DIM; c += 64) {
    float xv = xr[c];
    const float* w = rw + c * E_NUM;
#pragma unroll
    for (int e = 0; e < E_NUM; ++e) a[e] = fmaf(xv, w[e], a[e]);
  }
#pragma unroll
  for (int e = 0; e < E_NUM; ++e) {
#pragma unroll
    for (int off = 32; off > 0; off >>= 1) a[e] += __shfl_xor(a[e], off, 64);
  }
  if (lane == 0) {
    float p[E_NUM]; float m = -1e30f, s = 0.f;
#pragma unroll
    for (int e = 0; e < E_NUM; ++e) { p[e] = a[e] + rb[e]; m = fmaxf(m, p[e]); }
#pragma unroll
    for (int e = 0; e < E_NUM; ++e) { p[e] = expf(p[e] - m); s += p[e]; }
    const float inv = 1.f / s;
#pragma unroll
    for (int e = 0; e < E_NUM; ++e) p[e] *= inv;
    int e0 = 0; float v0 = p[0];
#pragma unroll
    for (int e = 1; e < E_NUM; ++e) if (p[e] > v0) { v0 = p[e]; e0 = e; }
    int e1 = -1; float v1 = -1e30f;
#pragma unroll
    for (int e = 0; e < E_NUM; ++e) if (e != e0 && p[e] > v1) { v1 = p[e]; e1 = e; }
    idx[2 * t] = e0; idx[2 * t + 1] = e1;
    vals[2 * t] = v0; vals[2 * t + 1] = v1;
    atomicAdd(&s_cnt[e0], 1u); atomicAdd(&s_cnt[e1], 1u);
#pragma unroll
    for (int e = 0; e < E_NUM; ++e) atomicAdd(&s_imp[e], p[e]);
  }
  __syncthreads();
  if (threadIdx.x < E_NUM) {
    atomicAdd(&cnt[threadIdx.x], s_cnt[threadIdx.x]);
    atomicAdd(&imp[threadIdx.x], s_imp[threadIdx.x]);
  }
}

__global__ void offsets_k(const u32* __restrict__ cnt, int* __restrict__ off) {
  if (threadIdx.x == 0) {
    int s = 0;
    for (int e = 0; e < E_NUM; ++e) { off[e] = s; s += (int)cnt[e]; }
    off[E_NUM] = s;
  }
}

// ---------------- scatter tokens into per-expert lists (stride N_TOK) ----------------
__global__ __launch_bounds__(256) void scatter_k(const int* __restrict__ idx, u32* __restrict__ cursor,
                                                 int* __restrict__ tl) {
  __shared__ u32 lcnt[E_NUM];
  __shared__ u32 base[E_NUM];
  if (threadIdx.x < E_NUM) lcnt[threadIdx.x] = 0u;
  __syncthreads();
  const int t = blockIdx.x * 256 + threadIdx.x;
  const int e0 = idx[2 * t], e1 = idx[2 * t + 1];
  const u32 p0 = atomicAdd(&lcnt[e0], 1u);
  const u32 p1 = atomicAdd(&lcnt[e1], 1u);
  __syncthreads();
  if (threadIdx.x < E_NUM) base[threadIdx.x] = atomicAdd(&cursor[threadIdx.x], lcnt[threadIdx.x]);
  __syncthreads();
  tl[e0 * N_TOK + (int)(base[e0] + p0)] = t;
  tl[e1 * N_TOK + (int)(base[e1] + p1)] = t;
}

// ---- bijective XCD-chunked grid remap (T1, m204): each XCD gets a contiguous x-fastest span ----
// With grid (128, ny, 8): chunk = nwg/8 = 128*ny -> each XCD owns exactly one expert's blocks,
// so its A rows and B panels live in that XCD's private L2.
__device__ __forceinline__ void xcd_remap(int& bx, int& by, int& bz) {
  const u32 nx = gridDim.x, ny = gridDim.y;
  const u32 n = nx * ny * gridDim.z;
  const u32 l = blockIdx.x + nx * (blockIdx.y + ny * blockIdx.z);
  const u32 q = n >> 3, r = n & 7;
  const u32 xcd = l & 7, i = l >> 3;
  const u32 wg = (xcd < r ? xcd * (q + 1) : r * (q + 1) + (xcd - r) * q) + i;
  bx = (int)(wg % nx);
  const u32 rest = wg / nx;
  by = (int)(rest % ny);
  bz = (int)(rest / ny);
}

// ---------------- grouped GEMM: 128x128 tile, BK=64, 4 waves, mfma 16x16x32 bf16 ----------------
// Round-1-verified structure (466 us/dispatch, MfmaUtil 25.9, 0 conflicts) + XCD remap.
// Staging: global_load_lds dwordx4 (16B/lane), linear LDS dest, XOR-swizzled SOURCE slot
// (slot ^= row&7) so that swizzled ds_read_b128 fragment reads are bank-conflict-free.
// MODE 0: h = relu(gather(x_bf) @ w1t^T + b1)  -> h_out (bf16)
// MODE 1: out_acc[token] += h @ w2t^T          (fp32 atomicAdd into d_out)
template <int MODE>
__global__ __launch_bounds__(256, 2) void moe_gemm(
    const u16* __restrict__ A_base, const u16* __restrict__ Bt, const float* __restrict__ bias,
    u16* __restrict__ h_out, float* out_acc, const int* __restrict__ token_list,
    const u32* __restrict__ counts, const int* __restrict__ offsets,
    int K_len, int B_stride, int B_ncap, int n_base, int k_off, int A_stride, int h_stride) {
  int bx, by, bz;
  xcd_remap(bx, by, bz);
  const int e = bz;
  const int n_e = (int)counts[e];
  const int m0 = bx * 128;
  if (m0 >= n_e) return;
  const int off_e = offsets[e];
  const int nb = by * 128;

  // LDS layout: [row(128)][k(64)] bf16, 128 B per row, 16 KB per matrix
  __shared__ u16 lA[128 * 64];
  __shared__ u16 lB[128 * 64];

  const int tid = threadIdx.x;
  const int lane = tid & 63;
  const int wave = tid >> 6;

  // Staging geometry: per K-step the 16 KB tile is filled in 4 rounds of
  // 256 threads x 16 B. Thread (wave,lane), round q writes LDS bytes
  // [q*4096 + wave*1024 + lane*16), i.e. row = q*32 + wave*8 + (lane>>3),
  // 16B-slot = lane&7. Source slot is XOR-swizzled by row&7 (== lane>>3).
  const int sub = lane >> 3;            // == row & 7 for every round
  const int c16 = lane & 7;             // LDS 16B-slot within row
  const int gslot = c16 ^ sub;          // swizzled global 16B-slot
  const u16* a_src[4];
  const u16* b_src[4];
#pragma unroll
  for (int q = 0; q < 4; ++q) {
    const int r = q * 32 + wave * 8 + sub;            // tile row 0..127
    int ar = m0 + r; if (ar > n_e - 1) ar = n_e - 1;  // clamp tail rows
    size_t arow;
    if (MODE == 0) arow = (size_t)token_list[e * N_TOK + ar] * A_stride;
    else           arow = (size_t)(off_e + ar) * A_stride;
    a_src[q] = A_base + arow + gslot * 8;
    b_src[q] = Bt + ((size_t)e * B_ncap + (n_base + nb + r)) * B_stride + k_off + gslot * 8;
  }

  f4 acc[4][4];
#pragma unroll
  for (int i = 0; i < 4; ++i)
#pragma unroll
    for (int j = 0; j < 4; ++j) acc[i][j] = (f4){0.f, 0.f, 0.f, 0.f};

  const int quad = lane >> 4, l16 = lane & 15;
  const int wm = (wave >> 1) * 64;
  const int wn = (wave & 1) * 64;
  const int p7 = l16 & 7;               // == fragment row & 7 (wm, i*16 are 0 mod 8)

  const int iters = K_len >> 6;
  for (int it = 0; it < iters; ++it) {
    // ---- stage current K-tile: 8 global_load_lds dwordx4 per thread ----
#pragma unroll
    for (int q = 0; q < 4; ++q) {
      __builtin_amdgcn_global_load_lds(
          (const AS1 void*)a_src[q],
          (AS3 void*)(&lA[q * 2048 + wave * 512]),
          16, 0, 0);
      __builtin_amdgcn_global_load_lds(
          (const AS1 void*)b_src[q],
          (AS3 void*)(&lB[q * 2048 + wave * 512]),
          16, 0, 0);
      a_src[q] += 64; b_src[q] += 64;
    }
    __syncthreads();   // drains vmcnt(0): tile resident

    // ---- compute: 2 k-substeps x 16 MFMA ----
#pragma unroll
    for (int kk = 0; kk < 2; ++kk) {
      const int sl = (((kk << 2) | quad) ^ p7) * 8;   // swizzled ds_read slot (u16 units)
      V16 af[4], bfr[4];
#pragma unroll
      for (int i = 0; i < 4; ++i) {
        af[i].f  = *(const f4*)&lA[(wm + i * 16 + l16) * 64 + sl];
        bfr[i].f = *(const f4*)&lB[(wn + i * 16 + l16) * 64 + sl];
      }
#pragma unroll
      for (int i = 0; i < 4; ++i)
#pragma unroll
        for (int j = 0; j < 4; ++j)
          acc[i][j] = __builtin_amdgcn_mfma_f32_16x16x32_bf16(af[i].b, bfr[j].b, acc[i][j], 0, 0, 0);
    }
    __syncthreads();   // all waves done reading before next overwrite
  }

  // epilogue; C/D layout: col = lane&15, row = quad*4 + reg
#pragma unroll
  for (int i = 0; i < 4; ++i) {
    const int lm = wm + i * 16 + quad * 4;
#pragma unroll
    for (int j = 0; j < 4; ++j) {
      const int ncol = nb + wn + j * 16 + l16;
#pragma unroll
      for (int r = 0; r < 4; ++r) {
        const int row = m0 + lm + r;
        if (row < n_e) {
          float v = acc[i][j][r];
          if (MODE == 0) {
            v += bias[e * H_DIM + n_base + ncol];
            v = fmaxf(v, 0.f);
            h_out[(size_t)(off_e + row) * h_stride + ncol] = f2bf(v);
          } else {
            const int tok = token_list[e * N_TOK + row];
            atomicAdd(&out_acc[(size_t)tok * C_DIM + ncol], v);
          }
        }
      }
    }
  }
}

// ---------------- final (in place on fp32 d_out): out = w*(acc + b2[e0] + b2[e1]); aux ----------------
__global__ __launch_bounds__(256) void final_k(float* out, const float* __restrict__ vals,
                                               const int* __restrict__ idx, const float* __restrict__ b2,
                                               const u32* __restrict__ cnt, const float* __restrict__ imp) {
  const size_t g = (size_t)blockIdx.x * 256 + threadIdx.x;  // over N*C/4
  const int t = (int)(g >> 8);
  const int c4 = (int)(g & 255);
  const float w = vals[t];  // faithful quirk: w_tok[t] = topk_vals.flat[t]
  const int e0 = idx[2 * t], e1 = idx[2 * t + 1];
  f4 a = ((const f4*)out)[g];
  f4 u = ((const f4*)(b2 + (size_t)e0 * C_DIM))[c4];
  f4 v = ((const f4*)(b2 + (size_t)e1 * C_DIM))[c4];
  f4 r;
#pragma unroll
  for (int q = 0; q < 4; ++q) r[q] = w * (a[q] + u[q] + v[q]);
  ((f4*)out)[g] = r;
  if (g == 0) {
    float aux = 0.f;
    for (int e = 0; e < E_NUM; ++e)
      aux += (imp[e] / (float)N_TOK) * ((float)cnt[e] / (float)(N_TOK * 2));
    out[(size_t)N_TOK * C_DIM] = aux;
  }
}

extern "C" void kernel_launch(void* const* d_in, const int* in_sizes, int n_in,
                              void* d_out, int out_size, void* d_ws, size_t ws_size,
                              hipStream_t stream) {
  const float* x  = (const float*)d_in[0];
  const float* rw = (const float*)d_in[1];
  const float* rb = (const float*)d_in[2];
  const float* w1 = (const float*)d_in[3];
  const float* b1 = (const float*)d_in[4];
  const float* w2 = (const float*)d_in[5];
  const float* b2 = (const float*)d_in[6];
  float* out = (float*)d_out;   // fp32 output (reference returns float32)

  char* ws = (char*)d_ws;
  size_t off = 0;
  auto alloc = [&](size_t bytes) -> void* {
    void* p = ws + off; off += (bytes + 255) & ~(size_t)255; return p;
  };
  u16* x_bf    = (u16*)alloc((size_t)N_TOK * C_DIM * 2);
  u16* w1t     = (u16*)alloc((size_t)E_NUM * H_DIM * C_DIM * 2);
  u16* w2t     = (u16*)alloc((size_t)E_NUM * C_DIM * H_DIM * 2);
  int* tl      = (int*)alloc((size_t)E_NUM * N_TOK * 4);
  int* idx     = (int*)alloc((size_t)N_TOK * 2 * 4);
  float* vals  = (float*)alloc((size_t)N_TOK * 2 * 4);
  u32* small   = (u32*)alloc(256);
  u32* cnt     = small;                 // [8]
  u32* cursor  = small + 8;             // [8]
  float* imp   = (float*)(small + 16);  // [8]
  int* offs    = (int*)(small + 24);    // [9]

  // h buffer: chunk H if workspace is tight
  size_t rem = (ws_size > off) ? ws_size - off : 0;
  int NC = 1;
  while (NC < 32 && (size_t)NK_TOT * (H_DIM / NC) * 2 > rem) NC <<= 1;
  const int Hc = H_DIM / NC;
  u16* h_buf = (u16*)(ws + off);

  // zero the fp32 accumulator (= d_out; timed replays poison it to 0xAA)
  hipMemsetAsync(out, 0, (size_t)out_size * sizeof(float), stream);
  hipMemsetAsync(small, 0, 256, stream);

  cvt_x_k<<<(N_TOK * C_DIM / 4) / 256, 256, 0, stream>>>(x, x_bf);
  transpose_cvt_k<<<dim3(H_DIM / 64, C_DIM / 64, E_NUM), 256, 0, stream>>>(w1, w1t, C_DIM, H_DIM);
  transpose_cvt_k<<<dim3(C_DIM / 64, H_DIM / 64, E_NUM), 256, 0, stream>>>(w2, w2t, H_DIM, C_DIM);
  router_k<<<N_TOK / 4, 256, 0, stream>>>(x, rw, rb, idx, vals, cnt, imp);
  offsets_k<<<1, 64, 0, stream>>>(cnt, offs);
  scatter_k<<<N_TOK / 256, 256, 0, stream>>>(idx, cursor, tl);

  for (int ci = 0; ci < NC; ++ci) {
    moe_gemm<0><<<dim3(128, Hc / 128, E_NUM), 256, 0, stream>>>(
        x_bf, w1t, b1, h_buf, nullptr, tl, cnt, offs,
        /*K_len*/ C_DIM, /*B_stride*/ C_DIM, /*B_ncap*/ H_DIM,
        /*n_base*/ ci * Hc, /*k_off*/ 0, /*A_stride*/ C_DIM, /*h_stride*/ Hc);
    moe_gemm<1><<<dim3(128, C_DIM / 128, E_NUM), 256, 0, stream>>>(
        h_buf, w2t, nullptr, nullptr, out, tl, cnt, offs,
        /*K_len*/ Hc, /*B_stride*/ H_DIM, /*B_ncap*/ C_DIM,
        /*n_base*/ 0, /*k_off*/ ci * Hc, /*A_stride*/ Hc, /*h_stride*/ 0);
  }

  final_k<<<(N_TOK * C_DIM / 4) / 256, 256, 0, stream>>>(out, vals, idx, b2, cnt, imp);
}